// Round 6
// baseline (44.432 us; speedup 1.0000x reference)
//
#include <hip/hip_runtime.h>

// SIMcLoss: x [8192, 256] fp32 -> scalar.
// loss = (||Xn^T Xn||_F^2 - n)/(n^2 - n) on the 256x256 Gram matrix.
// Single persistent kernel (160 blocks, manual grid barriers):
//   phase 0: row inv-norms (grid-strided waves) -> ws (agent atomics)
//   phase A: bf16(RNE) MFMA Gram tiles (10 sym pairs x 16 K-chunks),
//            slab partials via agent-scope stores (MALL-coherent)
//   phase B: per-element chunk-sum, weight, square, global reduce, ticket.
// Plus one 16-byte memset node for the barrier/sum words.
#define D 256
#define TILE 64
#define NPAIRS 10
#define CHUNK 512
#define NCHUNK 16
#define NBLK 160          // NPAIRS * NCHUNK; < 256 CUs -> co-resident
#define EPS 1e-8f

typedef __attribute__((ext_vector_type(8))) short bf16x8;
typedef __attribute__((ext_vector_type(4))) float f32x4;

__device__ __forceinline__ void pair_decode(int p, int& ta, int& tb) {
  if (p < 4)      { ta = 0; tb = p; }
  else if (p < 7) { ta = 1; tb = p - 3; }
  else if (p < 9) { ta = 2; tb = p - 5; }
  else            { ta = 3; tb = 3; }
}

// swizzled short-index into Xt[col][64 rows] (row-stride 64 shorts = 128 B).
__device__ __forceinline__ int swz(int col, int r) {
  int g = ((col >> 2) & 7) ^ ((col & 3) << 1);
  return col * 64 + (r ^ (g << 3));
}

// round-to-nearest-even fp32 -> bf16 (truncation would bias S)
__device__ __forceinline__ unsigned short rne_bf16(float f) {
  unsigned u = __float_as_uint(f);
  return (unsigned short)((u + 0x7fffu + ((u >> 16) & 1u)) >> 16);
}

// grid barrier: word pre-zeroed by memset node; release-arrive, acquire-spin.
__device__ __forceinline__ void gridbar(unsigned int* bar) {
  __syncthreads();
  if (threadIdx.x == 0) {
    __hip_atomic_fetch_add(bar, 1u, __ATOMIC_RELEASE,
                           __HIP_MEMORY_SCOPE_AGENT);
    while (__hip_atomic_load(bar, __ATOMIC_ACQUIRE,
                             __HIP_MEMORY_SCOPE_AGENT) < (unsigned)NBLK)
      __builtin_amdgcn_s_sleep(2);
  }
  __syncthreads();
}

__global__ __launch_bounds__(512) void k_main(
    const float* __restrict__ x, float* __restrict__ ws_inv,
    float* __restrict__ slabs, float* __restrict__ S,
    unsigned int* __restrict__ cnt, unsigned int* __restrict__ bar1,
    unsigned int* __restrict__ bar2, float* __restrict__ out, int N) {
  const int bx = blockIdx.x;
  const int pair = bx >> 4, chunk = bx & 15;
  int ta, tb; pair_decode(pair, ta, tb);
  const bool same = (ta == tb);
  const int row0 = chunk * CHUNK;
  const int tid = threadIdx.x;
  const int w = tid >> 6, lane = tid & 63;

  __shared__ short X[128 * 64];     // [col][row], cols 0..63=A, 64..127=B
  __shared__ float inv_s[CHUNK];
  __shared__ float red[4];

  // ---- phase 0: row inverse norms, grid-strided (one wave per row) ----
  for (int r = bx * 8 + w; r < N; r += NBLK * 8) {
    const float4 v = reinterpret_cast<const float4*>(x + (size_t)r * D)[lane];
    float s = v.x * v.x + v.y * v.y + v.z * v.z + v.w * v.w;
    #pragma unroll
    for (int o = 32; o > 0; o >>= 1) s += __shfl_xor(s, o);
    if (lane == 0)
      __hip_atomic_store(&ws_inv[r], 1.0f / fmaxf(sqrtf(s), EPS),
                         __ATOMIC_RELAXED, __HIP_MEMORY_SCOPE_AGENT);
  }
  gridbar(bar1);

  // ---- phase 0.5: this chunk's inv -> LDS ----
  inv_s[tid] = __hip_atomic_load(&ws_inv[row0 + tid], __ATOMIC_RELAXED,
                                 __HIP_MEMORY_SCOPE_AGENT);
  __syncthreads();

  // ---- phase A: staging + MFMA (round-5 validated structure) ----
  const int lcb = same ? 4 : 5;                 // log2(col-blocks)
  const int ntask = 16 << lcb;                  // 256 or 512
  const bool active = tid < ntask;
  const int c0 = (tid & ((1 << lcb) - 1)) << 2; // LDS col base
  const int r0 = (active ? (tid >> lcb) : 0) << 2;
  const int gc0 = (c0 < TILE) ? ta * TILE + c0 : tb * TILE + (c0 - TILE);

  const int i0 = (w >> 1) << 4;                 // 0,16,32,48
  const int j0 = (w & 1) << 5;                  // 0,32
  const int lm = lane & 15, lk = lane >> 4;
  const int bbase = same ? 0 : 64;

  f32x4 zero = {0.f, 0.f, 0.f, 0.f};
  f32x4 acc[2] = {zero, zero};

  float4 pv[4];
  if (active) {
    const float* xb = x + (size_t)(row0 + r0) * D + gc0;
    #pragma unroll
    for (int jj = 0; jj < 4; ++jj)
      pv[jj] = *reinterpret_cast<const float4*>(xb + (size_t)jj * D);
  }

  const int NSUB = CHUNK / 64;                  // 8
  for (int s = 0; s < NSUB; ++s) {
    if (active) {
      unsigned short hh[4][4];
      #pragma unroll
      for (int jj = 0; jj < 4; ++jj) {
        const float iv = inv_s[s * 64 + r0 + jj];
        const float vv[4] = {pv[jj].x, pv[jj].y, pv[jj].z, pv[jj].w};
        #pragma unroll
        for (int cc = 0; cc < 4; ++cc)
          hh[jj][cc] = rne_bf16(vv[cc] * iv);
      }
      #pragma unroll
      for (int cc = 0; cc < 4; ++cc)
        *reinterpret_cast<ushort4*>(&X[swz(c0 + cc, r0)]) =
            make_ushort4(hh[0][cc], hh[1][cc], hh[2][cc], hh[3][cc]);
      if (s + 1 < NSUB) {                       // prefetch next sub-chunk
        const float* xb = x + (size_t)(row0 + (s + 1) * 64 + r0) * D + gc0;
        #pragma unroll
        for (int jj = 0; jj < 4; ++jj)
          pv[jj] = *reinterpret_cast<const float4*>(xb + (size_t)jj * D);
      }
    }
    __syncthreads();
    #pragma unroll
    for (int rr = 0; rr < 64; rr += 32) {
      const int rbase = rr + lk * 8;
      bf16x8 A  = *reinterpret_cast<const bf16x8*>(&X[swz(i0 + lm, rbase)]);
      bf16x8 B0 = *reinterpret_cast<const bf16x8*>(&X[swz(bbase + j0 + lm, rbase)]);
      bf16x8 B1 = *reinterpret_cast<const bf16x8*>(&X[swz(bbase + j0 + 16 + lm, rbase)]);
      acc[0] = __builtin_amdgcn_mfma_f32_16x16x32_bf16(A, B0, acc[0], 0, 0, 0);
      acc[1] = __builtin_amdgcn_mfma_f32_16x16x32_bf16(A, B1, acc[1], 0, 0, 0);
    }
    __syncthreads();
  }

  // slab store via agent-scope atomics (coherent across in-kernel barrier)
  float* slab = slabs + (size_t)bx * (TILE * TILE);
  #pragma unroll
  for (int jt = 0; jt < 2; ++jt)
    #pragma unroll
    for (int rg = 0; rg < 4; ++rg)
      __hip_atomic_store(&slab[(i0 + lk * 4 + rg) * TILE + (j0 + jt * 16 + lm)],
                         acc[jt][rg], __ATOMIC_RELAXED,
                         __HIP_MEMORY_SCOPE_AGENT);
  gridbar(bar2);

  // ---- phase B: one G element per thread (160*256 = 40960 exactly) ----
  float part = 0.f;
  if (tid < 256) {
    const int e = ((bx * 256 + tid) & 4095);    // element within pair's tile
    const float* base = slabs + (size_t)(pair * NCHUNK) * (TILE * TILE) + e;
    float tot = 0.f;
    #pragma unroll
    for (int c = 0; c < NCHUNK; ++c)
      tot += __hip_atomic_load(&base[(size_t)c * (TILE * TILE)],
                               __ATOMIC_RELAXED, __HIP_MEMORY_SCOPE_AGENT);
    const bool diag = (pair == 0) | (pair == 4) | (pair == 7) | (pair == 9);
    part = (diag ? 1.f : 2.f) * tot * tot;
    #pragma unroll
    for (int o = 32; o > 0; o >>= 1) part += __shfl_xor(part, o);
    if (lane == 0) red[w] = part;
  }
  __syncthreads();
  if (tid == 0) {
    float blk = red[0] + red[1] + red[2] + red[3];
    atomicAdd(S, blk);
    __threadfence();
    unsigned int old = atomicAdd(cnt, 1u);
    if (old == (unsigned int)(NBLK - 1)) {
      float Sv = __hip_atomic_load(S, __ATOMIC_RELAXED,
                                   __HIP_MEMORY_SCOPE_AGENT);
      float nf = (float)N;
      out[0] = (Sv - nf) / (nf * nf - nf);
    }
  }
}

extern "C" void kernel_launch(void* const* d_in, const int* in_sizes, int n_in,
                              void* d_out, int out_size, void* d_ws, size_t ws_size,
                              hipStream_t stream) {
  const float* x = (const float*)d_in[0];
  float* out = (float*)d_out;
  const int N = in_sizes[0] / D;       // 8192

  // ws layout (floats): inv[N] | ctrl[64] (S, cnt, bar1, bar2) | slabs
  float* inv = (float*)d_ws;
  float* ctrl = inv + N;
  float* S = ctrl;
  unsigned int* cnt = (unsigned int*)(ctrl + 1);
  unsigned int* bar1 = (unsigned int*)(ctrl + 2);
  unsigned int* bar2 = (unsigned int*)(ctrl + 3);
  float* slabs = ctrl + 64;

  hipMemsetAsync(ctrl, 0, 16, stream);           // S, cnt, bar1, bar2
  k_main<<<dim3(NBLK), dim3(512), 0, stream>>>(
      x, inv, slabs, S, cnt, bar1, bar2, out, N);
}